// Round 1
// baseline (194.782 us; speedup 1.0000x reference)
//
#include <hip/hip_runtime.h>

#define TDIM 128   // TOKEN_DIM (reference constant)
#define VNUM 8     // VIRTUAL_NUM (reference constant)

// ---------------------------------------------------------------------------
// Kernel 1: build t = [token_list[attr_index]; zeros(V,d); vir_list]  (T x d)
//           write it to ws (for the sim kernel) AND to x_cat rows 0..T-1,
//           plus pass `query` through as floats.
// ---------------------------------------------------------------------------
__global__ void build_t_kernel(const float* __restrict__ token_list,
                               const float* __restrict__ vir_list,
                               const int*   __restrict__ attr_index,
                               const int*   __restrict__ query,
                               float* __restrict__ t_ws,
                               float* __restrict__ out_xcat,
                               float* __restrict__ out_query,
                               int A, int T, int NQ) {
    int idx = blockIdx.x * blockDim.x + threadIdx.x;
    int td = T * TDIM;
    if (idx < td) {
        int r = idx >> 7;      // / TDIM
        int c = idx & (TDIM - 1);
        float v;
        if (r < A) {
            v = token_list[attr_index[r] * TDIM + c];
        } else if (r < A + VNUM) {
            v = 0.0f;          // ws is poisoned 0xAA -> must write zeros
        } else {
            v = vir_list[(r - A - VNUM) * TDIM + c];
        }
        t_ws[idx] = v;
        out_xcat[idx] = v;
    } else if (idx < td + NQ) {
        int q = idx - td;
        out_query[q] = (float)query[q];
    }
}

// ---------------------------------------------------------------------------
// Kernel 2: token_sim = sigmoid(t @ t^T), inner_adj = (sim >= 0.01)
//           T*T = 6400 dot products of length 128 -- tiny, L1-resident.
// ---------------------------------------------------------------------------
__global__ void sim_kernel(const float* __restrict__ t_ws,
                           float* __restrict__ out_sim,
                           float* __restrict__ out_adj,
                           int T) {
    int idx = blockIdx.x * blockDim.x + threadIdx.x;
    if (idx >= T * T) return;
    int i = idx / T;
    int j = idx - i * T;
    const float4* a = (const float4*)(t_ws + i * TDIM);
    const float4* b = (const float4*)(t_ws + j * TDIM);
    float acc = 0.0f;
#pragma unroll
    for (int k = 0; k < TDIM / 4; ++k) {
        float4 av = a[k];
        float4 bv = b[k];
        acc += av.x * bv.x + av.y * bv.y + av.z * bv.z + av.w * bv.w;
    }
    float s = 1.0f / (1.0f + __expf(-acc));
    out_sim[idx] = s;
    out_adj[idx] = (s >= 0.01f) ? 1.0f : 0.0f;
}

// ---------------------------------------------------------------------------
// Kernel 3: the streaming bulk, fused into one grid-stride loop over 16B units:
//   seg X : copy x (N*d floats)              -> x_cat rows T..T+N-1
//   seg E : edge_index + T (int -> float)    -> shifted_edge_index
//   seg A : x_attr != 0   (int -> 0/1 float) -> attr_mask
// All segment base offsets are 16B-aligned (checked on host side).
// ---------------------------------------------------------------------------
__global__ void bulk_kernel(const float4* __restrict__ x4,
                            const int4*   __restrict__ e4,
                            const int4*   __restrict__ a4,
                            float4* __restrict__ out_x,
                            float4* __restrict__ out_e,
                            float4* __restrict__ out_a,
                            long nx4, long ne4, long na4, int T) {
    long stride = (long)gridDim.x * blockDim.x;
    long total  = nx4 + ne4 + na4;
    for (long i = (long)blockIdx.x * blockDim.x + threadIdx.x; i < total; i += stride) {
        if (i < nx4) {
            out_x[i] = x4[i];
        } else if (i < nx4 + ne4) {
            long j = i - nx4;
            int4 v = e4[j];
            float4 f;
            f.x = (float)(v.x + T);
            f.y = (float)(v.y + T);
            f.z = (float)(v.z + T);
            f.w = (float)(v.w + T);
            out_e[j] = f;
        } else {
            long j = i - nx4 - ne4;
            int4 v = a4[j];
            float4 f;
            f.x = (v.x != 0) ? 1.0f : 0.0f;
            f.y = (v.y != 0) ? 1.0f : 0.0f;
            f.z = (v.z != 0) ? 1.0f : 0.0f;
            f.w = (v.w != 0) ? 1.0f : 0.0f;
            out_a[j] = f;
        }
    }
}

extern "C" void kernel_launch(void* const* d_in, const int* in_sizes, int n_in,
                              void* d_out, int out_size, void* d_ws, size_t ws_size,
                              hipStream_t stream) {
    const float* x          = (const float*)d_in[0];
    const float* token_list = (const float*)d_in[1];
    const float* vir_list   = (const float*)d_in[2];
    const int*   attr_index = (const int*)d_in[3];
    const int*   x_attr     = (const int*)d_in[4];
    const int*   query      = (const int*)d_in[5];
    const int*   edge_index = (const int*)d_in[6];
    float* out = (float*)d_out;

    const int  d      = TDIM;
    const int  A      = in_sizes[3];          // 64
    const int  T      = A + 2 * VNUM;         // 80
    const long n_x    = (long)in_sizes[0];    // N*d = 64,000,000
    const long N      = n_x / d;              // 500,000
    const long n_attr = (long)in_sizes[4];    // N*A = 32,000,000
    const int  NQ     = in_sizes[5];          // 32
    const long n_edge = (long)in_sizes[6];    // 2*E = 16,000,000

    // Flat float32 output offsets, in reference return order.
    const long O_xcat  = 0;
    const long O_sim   = O_xcat + (T + N) * (long)d;
    const long O_adj   = O_sim + (long)T * T;
    const long O_edge  = O_adj + (long)T * T;
    const long O_attr  = O_edge + n_edge;
    const long O_query = O_attr + n_attr;

    float* t_ws = (float*)d_ws;               // T*d floats = 40 KB scratch

    const int td = T * d;
    const int threads1 = td + NQ;
    build_t_kernel<<<(threads1 + 255) / 256, 256, 0, stream>>>(
        token_list, vir_list, attr_index, query,
        t_ws, out + O_xcat, out + O_query, A, T, NQ);

    sim_kernel<<<(T * T + 255) / 256, 256, 0, stream>>>(
        t_ws, out + O_sim, out + O_adj, T);

    bulk_kernel<<<2048, 256, 0, stream>>>(
        (const float4*)x, (const int4*)edge_index, (const int4*)x_attr,
        (float4*)(out + O_xcat + td),   // x part of x_cat
        (float4*)(out + O_edge),
        (float4*)(out + O_attr),
        n_x / 4, n_edge / 4, n_attr / 4, T);
}

// Round 2
// 162.595 us; speedup vs baseline: 1.1980x; 1.1980x over previous
//
#include <hip/hip_runtime.h>

typedef float f4 __attribute__((ext_vector_type(4)));
typedef int   i4 __attribute__((ext_vector_type(4)));

#define TDIM 128   // TOKEN_DIM
#define VNUM 8     // VIRTUAL_NUM
#define NSPECIAL 26  // blocks 0..24: sim (25*256 = 6400 = T*T), block 25: t-writer

__global__ __launch_bounds__(256) void fused_kernel(
    const f4* __restrict__ x4,
    const i4* __restrict__ e4,
    const i4* __restrict__ a4,
    const float* __restrict__ token_list,
    const float* __restrict__ vir_list,
    const int*   __restrict__ attr_index,
    const int*   __restrict__ query,
    f4* __restrict__ ox4,          // x part of x_cat (rows T..T+N-1)
    f4* __restrict__ oe4,          // shifted_edge_index as float
    f4* __restrict__ oa4,          // attr_mask as float
    float* __restrict__ out_sim,   // token_sim [T*T]
    float* __restrict__ out_adj,   // inner_adj [T*T]
    float* __restrict__ out_t,     // t rows of x_cat [T*TDIM]
    float* __restrict__ out_query, // query as float [NQ]
    long nx4, long ne4, long na4,
    int A, int T, int NQ)
{
    const int bid = blockIdx.x;
    const int tid = threadIdx.x;

    if (bid >= NSPECIAL) {
        // ----- bulk: one float4 per thread, flat mapping, non-temporal -----
        long i = (long)(bid - NSPECIAL) * 256 + tid;
        if (i < nx4) {
            f4 v = __builtin_nontemporal_load(&x4[i]);
            __builtin_nontemporal_store(v, &ox4[i]);
        } else if (i < nx4 + ne4) {
            long j = i - nx4;
            i4 v = __builtin_nontemporal_load(&e4[j]);
            f4 f;
            f.x = (float)(v.x + T);
            f.y = (float)(v.y + T);
            f.z = (float)(v.z + T);
            f.w = (float)(v.w + T);
            __builtin_nontemporal_store(f, &oe4[j]);
        } else if (i < nx4 + ne4 + na4) {
            long j = i - nx4 - ne4;
            i4 v = __builtin_nontemporal_load(&a4[j]);
            f4 f;
            f.x = (v.x != 0) ? 1.0f : 0.0f;
            f.y = (v.y != 0) ? 1.0f : 0.0f;
            f.z = (v.z != 0) ? 1.0f : 0.0f;
            f.w = (v.w != 0) ? 1.0f : 0.0f;
            __builtin_nontemporal_store(f, &oa4[j]);
        }
        return;
    }

    if (bid < NSPECIAL - 1) {
        // ----- sim blocks: p = bid*256 + tid indexes the T*T sim matrix -----
        int p = bid * 256 + tid;
        if (p >= T * T) return;
        int i = p / T;
        int j = p - i * T;
        // source row pointer for t[r]: token gather / zeros / vir_list
        const float* pi;
        const float* pj;
        {
            int r = i;
            pi = (r < A) ? token_list + (long)attr_index[r] * TDIM
               : (r < A + VNUM) ? (const float*)0
               : vir_list + (long)(r - A - VNUM) * TDIM;
            r = j;
            pj = (r < A) ? token_list + (long)attr_index[r] * TDIM
               : (r < A + VNUM) ? (const float*)0
               : vir_list + (long)(r - A - VNUM) * TDIM;
        }
        float acc = 0.0f;
        if (pi && pj) {
            const f4* a = (const f4*)pi;
            const f4* b = (const f4*)pj;
#pragma unroll
            for (int k = 0; k < TDIM / 4; ++k) {
                f4 av = a[k];
                f4 bv = b[k];
                acc += av.x * bv.x + av.y * bv.y + av.z * bv.z + av.w * bv.w;
            }
        }
        float s = 1.0f / (1.0f + __expf(-acc));
        out_sim[p] = s;
        out_adj[p] = (s >= 0.01f) ? 1.0f : 0.0f;
        return;
    }

    // ----- t-writer block: t rows of x_cat + query passthrough -----
    for (int e = tid; e < T * TDIM; e += 256) {
        int r = e >> 7;            // / TDIM
        int c = e & (TDIM - 1);
        float v = (r < A) ? token_list[(long)attr_index[r] * TDIM + c]
                : (r < A + VNUM) ? 0.0f
                : vir_list[(long)(r - A - VNUM) * TDIM + c];
        out_t[e] = v;
    }
    if (tid < NQ) out_query[tid] = (float)query[tid];
}

extern "C" void kernel_launch(void* const* d_in, const int* in_sizes, int n_in,
                              void* d_out, int out_size, void* d_ws, size_t ws_size,
                              hipStream_t stream) {
    const float* x          = (const float*)d_in[0];
    const float* token_list = (const float*)d_in[1];
    const float* vir_list   = (const float*)d_in[2];
    const int*   attr_index = (const int*)d_in[3];
    const int*   x_attr     = (const int*)d_in[4];
    const int*   query      = (const int*)d_in[5];
    const int*   edge_index = (const int*)d_in[6];
    float* out = (float*)d_out;

    const int  d      = TDIM;
    const int  A      = in_sizes[3];          // 64
    const int  T      = A + 2 * VNUM;         // 80
    const long n_x    = (long)in_sizes[0];    // N*d
    const long N      = n_x / d;
    const long n_attr = (long)in_sizes[4];    // N*A
    const int  NQ     = in_sizes[5];
    const long n_edge = (long)in_sizes[6];    // 2*E

    // Flat float32 output offsets, reference return order.
    const long O_xcat  = 0;
    const long O_sim   = O_xcat + (T + N) * (long)d;
    const long O_adj   = O_sim + (long)T * T;
    const long O_edge  = O_adj + (long)T * T;
    const long O_attr  = O_edge + n_edge;
    const long O_query = O_attr + n_attr;

    const long nx4 = n_x / 4, ne4 = n_edge / 4, na4 = n_attr / 4;
    const long bulk_blocks = (nx4 + ne4 + na4 + 255) / 256;
    const long grid = NSPECIAL + bulk_blocks;

    fused_kernel<<<(int)grid, 256, 0, stream>>>(
        (const f4*)x, (const i4*)edge_index, (const i4*)x_attr,
        token_list, vir_list, attr_index, query,
        (f4*)(out + O_xcat + (long)T * d),
        (f4*)(out + O_edge),
        (f4*)(out + O_attr),
        out + O_sim, out + O_adj, out + O_xcat, out + O_query,
        nx4, ne4, na4, A, T, NQ);
}

// Round 3
// 151.338 us; speedup vs baseline: 1.2871x; 1.0744x over previous
//
#include <hip/hip_runtime.h>

typedef float f4 __attribute__((ext_vector_type(4)));
typedef int   i4 __attribute__((ext_vector_type(4)));

#define TDIM 128     // TOKEN_DIM
#define VNUM 8       // VIRTUAL_NUM
#define NSIM 25      // blocks 0..24: sim (25*256 = 6400 = T*T)
#define NSPECIAL 26  // + block 25: t-writer/query
#define VPT 4        // float4s per thread in bulk
#define BLK_ELEMS (256 * VPT)   // float4s per bulk block

__global__ __launch_bounds__(256) void fused_kernel(
    const f4* __restrict__ x4,
    const i4* __restrict__ e4,
    const i4* __restrict__ a4,
    const float* __restrict__ token_list,
    const float* __restrict__ vir_list,
    const int*   __restrict__ attr_index,
    const int*   __restrict__ query,
    f4* __restrict__ ox4,          // x part of x_cat (rows T..T+N-1)
    f4* __restrict__ oe4,          // shifted_edge_index as float
    f4* __restrict__ oa4,          // attr_mask as float
    float* __restrict__ out_sim,   // token_sim [T*T]
    float* __restrict__ out_adj,   // inner_adj [T*T]
    float* __restrict__ out_t,     // t rows of x_cat [T*TDIM]
    float* __restrict__ out_query, // query as float [NQ]
    long nx4, long ne4, long na4,
    long xb, long eb,              // block counts for x / edge segments
    int A, int T, int NQ)
{
    const int bid = blockIdx.x;
    const int tid = threadIdx.x;

    if (bid >= NSPECIAL) {
        long b = bid - NSPECIAL;
        if (b < xb) {
            // ----- x copy: 4 x float4 per thread, loads batched -----
            long base = b * BLK_ELEMS + tid;
            f4 v[VPT];
#pragma unroll
            for (int u = 0; u < VPT; ++u) {
                long i = base + (long)u * 256;
                if (i < nx4) v[u] = __builtin_nontemporal_load(&x4[i]);
            }
#pragma unroll
            for (int u = 0; u < VPT; ++u) {
                long i = base + (long)u * 256;
                if (i < nx4) __builtin_nontemporal_store(v[u], &ox4[i]);
            }
        } else if (b < xb + eb) {
            // ----- edge_index + T, int -> float -----
            long base = (b - xb) * BLK_ELEMS + tid;
            i4 v[VPT];
#pragma unroll
            for (int u = 0; u < VPT; ++u) {
                long i = base + (long)u * 256;
                if (i < ne4) v[u] = __builtin_nontemporal_load(&e4[i]);
            }
#pragma unroll
            for (int u = 0; u < VPT; ++u) {
                long i = base + (long)u * 256;
                if (i < ne4) {
                    f4 f;
                    f.x = (float)(v[u].x + T);
                    f.y = (float)(v[u].y + T);
                    f.z = (float)(v[u].z + T);
                    f.w = (float)(v[u].w + T);
                    __builtin_nontemporal_store(f, &oe4[i]);
                }
            }
        } else {
            // ----- x_attr != 0 -> 0/1 float -----
            long base = (b - xb - eb) * BLK_ELEMS + tid;
            i4 v[VPT];
#pragma unroll
            for (int u = 0; u < VPT; ++u) {
                long i = base + (long)u * 256;
                if (i < na4) v[u] = __builtin_nontemporal_load(&a4[i]);
            }
#pragma unroll
            for (int u = 0; u < VPT; ++u) {
                long i = base + (long)u * 256;
                if (i < na4) {
                    f4 f;
                    f.x = (v[u].x != 0) ? 1.0f : 0.0f;
                    f.y = (v[u].y != 0) ? 1.0f : 0.0f;
                    f.z = (v[u].z != 0) ? 1.0f : 0.0f;
                    f.w = (v[u].w != 0) ? 1.0f : 0.0f;
                    __builtin_nontemporal_store(f, &oa4[i]);
                }
            }
        }
        return;
    }

    if (bid < NSIM) {
        // ----- sim blocks: p = bid*256 + tid indexes the T*T sim matrix -----
        int p = bid * 256 + tid;
        if (p >= T * T) return;
        int i = p / T;
        int j = p - i * T;
        const float* pi;
        const float* pj;
        {
            int r = i;
            pi = (r < A) ? token_list + (long)attr_index[r] * TDIM
               : (r < A + VNUM) ? (const float*)0
               : vir_list + (long)(r - A - VNUM) * TDIM;
            r = j;
            pj = (r < A) ? token_list + (long)attr_index[r] * TDIM
               : (r < A + VNUM) ? (const float*)0
               : vir_list + (long)(r - A - VNUM) * TDIM;
        }
        float acc = 0.0f;
        if (pi && pj) {
            const f4* a = (const f4*)pi;
            const f4* b = (const f4*)pj;
#pragma unroll
            for (int k = 0; k < TDIM / 4; ++k) {
                f4 av = a[k];
                f4 bv = b[k];
                acc += av.x * bv.x + av.y * bv.y + av.z * bv.z + av.w * bv.w;
            }
        }
        float s = 1.0f / (1.0f + __expf(-acc));
        out_sim[p] = s;
        out_adj[p] = (s >= 0.01f) ? 1.0f : 0.0f;
        return;
    }

    // ----- t-writer block: t rows of x_cat + query passthrough -----
    for (int e = tid; e < T * TDIM; e += 256) {
        int r = e >> 7;            // / TDIM
        int c = e & (TDIM - 1);
        float v = (r < A) ? token_list[(long)attr_index[r] * TDIM + c]
                : (r < A + VNUM) ? 0.0f
                : vir_list[(long)(r - A - VNUM) * TDIM + c];
        out_t[e] = v;
    }
    if (tid < NQ) out_query[tid] = (float)query[tid];
}

extern "C" void kernel_launch(void* const* d_in, const int* in_sizes, int n_in,
                              void* d_out, int out_size, void* d_ws, size_t ws_size,
                              hipStream_t stream) {
    const float* x          = (const float*)d_in[0];
    const float* token_list = (const float*)d_in[1];
    const float* vir_list   = (const float*)d_in[2];
    const int*   attr_index = (const int*)d_in[3];
    const int*   x_attr     = (const int*)d_in[4];
    const int*   query      = (const int*)d_in[5];
    const int*   edge_index = (const int*)d_in[6];
    float* out = (float*)d_out;

    const int  d      = TDIM;
    const int  A      = in_sizes[3];          // 64
    const int  T      = A + 2 * VNUM;         // 80
    const long n_x    = (long)in_sizes[0];    // N*d
    const long N      = n_x / d;
    const long n_attr = (long)in_sizes[4];    // N*A
    const int  NQ     = in_sizes[5];
    const long n_edge = (long)in_sizes[6];    // 2*E

    // Flat float32 output offsets, reference return order.
    const long O_xcat  = 0;
    const long O_sim   = O_xcat + (T + N) * (long)d;
    const long O_adj   = O_sim + (long)T * T;
    const long O_edge  = O_adj + (long)T * T;
    const long O_attr  = O_edge + n_edge;
    const long O_query = O_attr + n_attr;

    const long nx4 = n_x / 4, ne4 = n_edge / 4, na4 = n_attr / 4;
    const long xb = (nx4 + BLK_ELEMS - 1) / BLK_ELEMS;
    const long eb = (ne4 + BLK_ELEMS - 1) / BLK_ELEMS;
    const long ab = (na4 + BLK_ELEMS - 1) / BLK_ELEMS;
    const long grid = NSPECIAL + xb + eb + ab;

    fused_kernel<<<(int)grid, 256, 0, stream>>>(
        (const f4*)x, (const i4*)edge_index, (const i4*)x_attr,
        token_list, vir_list, attr_index, query,
        (f4*)(out + O_xcat + (long)T * d),
        (f4*)(out + O_edge),
        (f4*)(out + O_attr),
        out + O_sim, out + O_adj, out + O_xcat, out + O_query,
        nx4, ne4, na4, xb, eb, A, T, NQ);
}